// Round 9
// baseline (63.055 us; speedup 1.0000x reference)
//
#include <hip/hip_runtime.h>

#define H_DIM 3072
#define W_DIM 3072
#define TW 32
#define TH 32
#define BB_ROWS 42     // 31*(cos+sin)+2 <= 42 rows incl. the r1 tap, theta in [0,20deg]
#define BB_STRIDE 133  // 42 cols * 3ch = 126 + 7 pad; 133 mod 32 = 5 (odd) spreads banks
                       // R4 measured: 3.5e5 conflicts with this stride (vs 1.1e7 at 132/204)

typedef float f32x4 __attribute__((ext_vector_type(4)));
typedef f32x4 __attribute__((aligned(4))) f32x4u;  // global segment bases are 4B-aligned

__global__ __launch_bounds__(256) void rotation_kernel(
    const float* __restrict__ img,     // (H, W, 3) f32
    const float* __restrict__ fv,      // (1,) f32
    float* __restrict__ out)           // (H, W, 3) f32
{
    __shared__ float S[BB_ROWS * BB_STRIDE];   // 22,344 B -> 7 blocks/CU (28 waves)

    const int tx = threadIdx.x;   // 0..7  : 4 consecutive px each
    const int ty = threadIdx.y;   // 0..31
    const int C0 = blockIdx.x * TW;
    const int R0 = blockIdx.y * TH;

    // theta in [0, 0.349] rad; HW trig absmax identical to libm (R5 evidence)
    const float theta = fv[0] * 20.0f * (3.14159265358979323846f / 180.0f);
    const float ct = __cosf(theta);
    const float st = __sinf(theta);

    const float o_r = (float)H_DIM / 2.0f + 0.5f;
    const float o_c = (float)W_DIM / 2.0f + 0.5f;

    // ---- block-uniform bbox from the 4 tile corners ----
    const float drA = (float)R0 - o_r, drB = (float)(R0 + TH - 1) - o_r;
    const float dcA = (float)C0 - o_c, dcB = (float)(C0 + TW - 1) - o_c;
    float min_r = 1e30f, max_r = -1e30f, min_c = 1e30f, max_c = -1e30f;
    #pragma unroll
    for (int k = 0; k < 4; ++k) {
        const float dr = (k & 1) ? drB : drA;
        const float dc = (k & 2) ? dcB : dcA;
        const float sr = ct * dr - st * dc + o_r;
        const float sc = st * dr + ct * dc + o_c;
        min_r = fminf(min_r, sr); max_r = fmaxf(max_r, sr);
        min_c = fminf(min_c, sc); max_c = fmaxf(max_c, sc);
    }
    // interior: every unclamped tap (r0..r0+1, c0..c0+1) is in-image
    const bool interior = (min_r > 0.01f) & (max_r < (float)(H_DIM - 2) - 0.01f) &
                          (min_c > 0.01f) & (max_c < (float)(W_DIM - 2) - 0.01f);

    const int r_lo = min(max((int)floorf(min_r), 0), H_DIM - 1);
    const int c_lo = min(max((int)floorf(min_c), 0), W_DIM - 1);
    const int r_hi = min(min(max((int)floorf(max_r), 0), H_DIM - 1) + 1, H_DIM - 1);
    const int c_hi = min(min(max((int)floorf(max_c), 0), W_DIM - 1) + 1, W_DIM - 1);
    const int nrows = r_hi - r_lo + 1;          // <= 42
    const int nflt  = (c_hi - c_lo + 1) * 3;    // <= 126
    const int nflt4 = nflt >> 2;
    const int rem   = nflt & 3;

    // ---- stage bbox into LDS (dense f32x4 global reads; 4B LDS writes merge
    //      to ds_write2_b32; odd stride so b128 alignment is impossible anyway) ----
    for (int yy = ty; yy < nrows; yy += 32) {
        const float* src = img + ((size_t)(r_lo + yy) * W_DIM + c_lo) * 3;
        float* dst = S + yy * BB_STRIDE;
        for (int xx = tx; xx < nflt4; xx += 8) {
            const f32x4u v = *(const f32x4u*)(src + xx * 4);
            dst[xx * 4 + 0] = v[0];
            dst[xx * 4 + 1] = v[1];
            dst[xx * 4 + 2] = v[2];
            dst[xx * 4 + 3] = v[3];
        }
        if (tx < rem) dst[nflt4 * 4 + tx] = src[nflt4 * 4 + tx];
        if (tx < 6)   dst[nflt + tx] = 0.0f;   // degenerate-border windows read zeros
    }
    __syncthreads();

    // ---- gather from LDS ----
    const int r = R0 + ty;
    const int cbase = C0 + tx * 4;
    const float drr = (float)r - o_r;
    const float sr0 = ct * drr - st * ((float)cbase - o_c) + o_r;
    const float sc0 = st * drr + ct * ((float)cbase - o_c) + o_c;
    const int K = r_lo * BB_STRIDE + c_lo * 3;

    float res[12];

    if (interior) {
        #pragma unroll
        for (int p = 0; p < 4; ++p) {
            const float src_r = sr0 - st * (float)p;   // d(src_r)/dc = -st
            const float src_c = sc0 + ct * (float)p;   // d(src_c)/dc = +ct
            const float r0f = floorf(src_r);
            const float c0f = floorf(src_c);
            const float wr = src_r - r0f;
            const float wc = src_c - c0f;
            const float* s0 = S + ((int)r0f * BB_STRIDE + (int)c0f * 3 - K);
            const float* s1 = s0 + BB_STRIDE;          // r1 = r0+1, always staged
            // 6 consecutive floats per row -> 3x ds_read2_b32 each
            #pragma unroll
            for (int ch = 0; ch < 3; ++ch) {
                const float row0 = s0[ch] + wc * (s0[3 + ch] - s0[ch]);
                const float row1 = s1[ch] + wc * (s1[3 + ch] - s1[ch]);
                res[p * 3 + ch] = row0 + wr * (row1 - row0);
            }
        }
    } else {
        #pragma unroll
        for (int p = 0; p < 4; ++p) {
            float src_r = sr0 - st * (float)p;
            float src_c = sc0 + ct * (float)p;
            src_r = fminf(fmaxf(src_r, 0.0f), (float)(H_DIM - 1));
            src_c = fminf(fmaxf(src_c, 0.0f), (float)(W_DIM - 1));
            const float r0f = floorf(src_r);
            const float c0f = floorf(src_c);
            const float wr = src_r - r0f;
            const float wc = src_c - c0f;
            const int r0 = (int)r0f;
            const int c0 = (int)c0f;
            const int r1 = min(r0 + 1, H_DIM - 1);
            int cb = max(min(c0, c_hi - 1), c_lo);   // 2-col window base in staged range
            const bool hi = (c0 > cb);               // right-edge clamp: wc==0 there
            const int ly0 = min(max(r0 - r_lo, 0), BB_ROWS - 1);
            const int ly1 = min(max(r1 - r_lo, 0), BB_ROWS - 1);
            const int lx  = min(max((cb - c_lo) * 3, 0), BB_STRIDE - 6);
            const float* s0 = S + ly0 * BB_STRIDE + lx;
            const float* s1 = S + ly1 * BB_STRIDE + lx;
            float q00 = s0[0], q01 = s0[1], q02 = s0[2], q03 = s0[3], q04 = s0[4], q05 = s0[5];
            float q10 = s1[0], q11 = s1[1], q12 = s1[2], q13 = s1[3], q14 = s1[4], q15 = s1[5];
            if (hi) { q00 = q03; q01 = q04; q02 = q05; q10 = q13; q11 = q14; q12 = q15; }
            float row0, row1;
            row0 = q00 + wc * (q03 - q00); row1 = q10 + wc * (q13 - q10);
            res[p * 3 + 0] = row0 + wr * (row1 - row0);
            row0 = q01 + wc * (q04 - q01); row1 = q11 + wc * (q14 - q11);
            res[p * 3 + 1] = row0 + wr * (row1 - row0);
            row0 = q02 + wc * (q05 - q02); row1 = q12 + wc * (q15 - q12);
            res[p * 3 + 2] = row0 + wr * (row1 - row0);
        }
    }

    // 48 contiguous bytes/thread, 16B-aligned: 3x dwordx4 normal stores
    // (nontemporal cost +35MB HBM writes in R8 — reverted)
    f32x4* op = (f32x4*)(out + ((size_t)r * W_DIM + cbase) * 3);
    op[0] = (f32x4){res[0], res[1], res[2],  res[3]};
    op[1] = (f32x4){res[4], res[5], res[6],  res[7]};
    op[2] = (f32x4){res[8], res[9], res[10], res[11]};
}

extern "C" void kernel_launch(void* const* d_in, const int* in_sizes, int n_in,
                              void* d_out, int out_size, void* d_ws, size_t ws_size,
                              hipStream_t stream) {
    const float* img = (const float*)d_in[0];
    const float* fv  = (const float*)d_in[1];
    float* out = (float*)d_out;

    dim3 block(8, 32, 1);
    dim3 grid(W_DIM / TW, H_DIM / TH, 1);
    rotation_kernel<<<grid, block, 0, stream>>>(img, fv, out);
}

// Round 10
// 40.021 us; speedup vs baseline: 1.5755x; 1.5755x over previous
//
#include <hip/hip_runtime.h>

#define H_DIM 3072
#define W_DIM 3072

// 4B-aligned vector types: tap base addrs ((r*W+c)*3 floats) are only 4B-aligned.
typedef float f32x4 __attribute__((ext_vector_type(4)));
typedef float f32x2 __attribute__((ext_vector_type(2)));
typedef f32x4 __attribute__((aligned(4))) f32x4u;
typedef f32x2 __attribute__((aligned(4))) f32x2u;

__global__ __launch_bounds__(256) void rotation_kernel(
    const float* __restrict__ img,     // (H, W, 3) f32
    const float* __restrict__ fv,      // (1,) f32
    float* __restrict__ out)           // (H, W, 3) f32
{
    // 1 px/thread; wave = 64 CONSECUTIVE columns -> tap lane-stride 12B,
    // so one tap instr touches ~13-25 cache lines instead of ~50 (R5).
    const int c = blockIdx.x * 64 + threadIdx.x;
    const int r = blockIdx.y * 4 + threadIdx.y;

    // theta in [0, 0.349] rad; HW trig absmax identical to libm (R5 evidence)
    const float theta = fv[0] * 20.0f * (3.14159265358979323846f / 180.0f);
    const float ct = __cosf(theta);
    const float st = __sinf(theta);

    const float o_r = (float)H_DIM / 2.0f + 0.5f;   // 1536.5
    const float o_c = (float)W_DIM / 2.0f + 0.5f;

    float src_r = ct * ((float)r - o_r) - st * ((float)c - o_c) + o_r;
    float src_c = st * ((float)r - o_r) + ct * ((float)c - o_c) + o_c;
    src_r = fminf(fmaxf(src_r, 0.0f), (float)(H_DIM - 1));
    src_c = fminf(fmaxf(src_c, 0.0f), (float)(W_DIM - 1));

    // Window-base trick (replaces border selects): base = min(floor, dim-2),
    // weight = src - base. Interior: identical to reference. At the clamped
    // edge (floor == dim-1, ref weight 0): base shifts back one, weight
    // becomes exactly 1.0, and the blend selects the far tap = edge pixel.
    const int rb = min((int)src_r, H_DIM - 2);   // src_r >= 0 -> (int) == floor
    const int cb = min((int)src_c, W_DIM - 2);
    const float wr = src_r - (float)rb;
    const float wc = src_c - (float)cb;

    const float* rp0 = img + (size_t)(rb * W_DIM + cb) * 3;
    const float* rp1 = rp0 + (size_t)W_DIM * 3;

    // 6 consecutive floats per tap row: f32x4 + f32x2 (2 instrs/row)
    const f32x4u A0 = *(const f32x4u*)rp0;
    const f32x2u B0 = *(const f32x2u*)(rp0 + 4);
    const f32x4u A1 = *(const f32x4u*)rp1;
    const f32x2u B1 = *(const f32x2u*)(rp1 + 4);

    const float q0[6] = {A0[0], A0[1], A0[2], A0[3], B0[0], B0[1]};
    const float q1[6] = {A1[0], A1[1], A1[2], A1[3], B1[0], B1[1]};

    float res[3];
    #pragma unroll
    for (int ch = 0; ch < 3; ++ch) {
        const float row0 = q0[ch] + wc * (q0[3 + ch] - q0[ch]);
        const float row1 = q1[ch] + wc * (q1[3 + ch] - q1[ch]);
        res[ch] = row0 + wr * (row1 - row0);
    }

    // 12B/px, wave-contiguous 768B: compiler merges to dwordx2+dword
    float* o = out + ((size_t)r * W_DIM + c) * 3;
    o[0] = res[0];
    o[1] = res[1];
    o[2] = res[2];
}

extern "C" void kernel_launch(void* const* d_in, const int* in_sizes, int n_in,
                              void* d_out, int out_size, void* d_ws, size_t ws_size,
                              hipStream_t stream) {
    const float* img = (const float*)d_in[0];
    const float* fv  = (const float*)d_in[1];
    float* out = (float*)d_out;

    dim3 block(64, 4, 1);
    dim3 grid(W_DIM / 64, H_DIM / 4, 1);
    rotation_kernel<<<grid, block, 0, stream>>>(img, fv, out);
}